// Round 4
// baseline (767.710 us; speedup 1.0000x reference)
//
#include <hip/hip_runtime.h>
#include <cstdint>
#include <cstddef>

// Problem constants
#define T_TOK 8192
#define HDIM  1024
#define FDIM  2048
#define NEXP  16
#define CAP   1280

typedef __bf16 bf16x8 __attribute__((ext_vector_type(8)));
typedef float  f32x4  __attribute__((ext_vector_type(4)));

__device__ inline void gld16(const void* g, void* l) {
  __builtin_amdgcn_global_load_lds(
      (__attribute__((address_space(1))) void*)g,
      (__attribute__((address_space(3))) void*)l, 16, 0, 0);
}

// ---------------- Router: one wave per token ----------------
__global__ __launch_bounds__(256) void router_kernel(
    const float* __restrict__ x, const float* __restrict__ wr,
    int* __restrict__ eidx, float* __restrict__ eprob) {
  int t = blockIdx.x * 4 + (threadIdx.x >> 6);
  int lane = threadIdx.x & 63;
  float acc[NEXP];
#pragma unroll
  for (int e = 0; e < NEXP; ++e) acc[e] = 0.f;
  const float4* xp = (const float4*)(x + (size_t)t * HDIM + lane * 16);
#pragma unroll
  for (int q = 0; q < 4; ++q) {
    float4 xv = xp[q];
    float xa[4] = {xv.x, xv.y, xv.z, xv.w};
#pragma unroll
    for (int ii = 0; ii < 4; ++ii) {
      int h = lane * 16 + q * 4 + ii;
      const float4* wp = (const float4*)(wr + (size_t)h * NEXP);
      float w[NEXP];
      float4 w0 = wp[0], w1 = wp[1], w2 = wp[2], w3 = wp[3];
      w[0]=w0.x; w[1]=w0.y; w[2]=w0.z; w[3]=w0.w;
      w[4]=w1.x; w[5]=w1.y; w[6]=w1.z; w[7]=w1.w;
      w[8]=w2.x; w[9]=w2.y; w[10]=w2.z; w[11]=w2.w;
      w[12]=w3.x; w[13]=w3.y; w[14]=w3.z; w[15]=w3.w;
#pragma unroll
      for (int e = 0; e < NEXP; ++e) acc[e] += xa[ii] * w[e];
    }
  }
#pragma unroll
  for (int e = 0; e < NEXP; ++e) {
#pragma unroll
    for (int s = 32; s > 0; s >>= 1) acc[e] += __shfl_xor(acc[e], s);
  }
  if (lane == 0) {
    float l0 = -1e30f, l1 = -1e30f; int i0 = 0, i1 = 0;
#pragma unroll
    for (int e = 0; e < NEXP; ++e) {
      float v = acc[e];
      if (v > l0) { l1 = l0; i1 = i0; l0 = v; i0 = e; }
      else if (v > l1) { l1 = v; i1 = e; }
    }
    float p0 = 1.f / (1.f + __expf(l1 - l0));  // == softmax-then-renorm over top2
    eidx[t * 2 + 0] = i0; eidx[t * 2 + 1] = i1;
    eprob[t * 2 + 0] = p0; eprob[t * 2 + 1] = 1.f - p0;
  }
}

// ------------- Positions: single block, deterministic prefix count -------------
// Counters live in LDS (scan[tid][e]); the old per-thread cnt[]/basec[] arrays were
// runtime-indexed register arrays -> scratch RMW (rule #20), serializing this
// single-block kernel on local-memory latency.
__global__ __launch_bounds__(256) void pos_kernel(
    const int* __restrict__ eidx, const float* __restrict__ eprob,
    int* __restrict__ slot_token, float* __restrict__ slot_prob) {
  __shared__ int scan[256][NEXP];
  int tid = threadIdx.x;
#pragma unroll
  for (int e = 0; e < NEXP; ++e) scan[tid][e] = 0;
  int base_i = tid * 64;
  const int4* ep = (const int4*)(eidx + base_i);
  for (int i = 0; i < 16; ++i) {
    int4 v = ep[i];
    scan[tid][v.x]++; scan[tid][v.y]++; scan[tid][v.z]++; scan[tid][v.w]++;
  }
  __syncthreads();
  if (tid < NEXP) {
    int run = 0;
    for (int i = 0; i < 256; ++i) { int v = scan[i][tid]; scan[i][tid] = run; run += v; }
  }
  __syncthreads();
  for (int i = 0; i < 64; ++i) {
    int fi = base_i + i;
    int e = eidx[fi];
    int p = scan[tid][e]++;
    if (p < CAP) {
      slot_token[e * CAP + p] = fi >> 1;   // token id
      slot_prob[e * CAP + p] = eprob[fi];
    }
  }
}

// ------- Scatter x rows into K-CHUNKED bf16 dispatch buffer (zeros for empty) -------
// disp layout: [E][KA=16][CAP][64] — element (e, m, h) at ((e*16 + h/64)*CAP + m)*64 + h%64.
__global__ __launch_bounds__(256) void scatter_kernel(
    const float* __restrict__ x, const int* __restrict__ slot_token,
    __bf16* __restrict__ disp) {
  int s = blockIdx.x * 4 + (threadIdx.x >> 6);
  int lane = threadIdx.x & 63;
  int e = s / CAP, m = s % CAP;
  int tok = slot_token[s];
  __bf16 vals[16] __attribute__((aligned(16)));
  if (tok >= 0) {
    const float4* xp = (const float4*)(x + (size_t)tok * HDIM + lane * 16);
#pragma unroll
    for (int q = 0; q < 4; ++q) {
      float4 v = xp[q];
      vals[q * 4 + 0] = (__bf16)v.x; vals[q * 4 + 1] = (__bf16)v.y;
      vals[q * 4 + 2] = (__bf16)v.z; vals[q * 4 + 3] = (__bf16)v.w;
    }
  } else {
#pragma unroll
    for (int q = 0; q < 16; ++q) vals[q] = (__bf16)0.f;
  }
  uint4* dst = (uint4*)(disp + (((size_t)e * 16 + (lane >> 2)) * CAP + m) * 64 + (lane & 3) * 16);
  dst[0] = ((uint4*)vals)[0];
  dst[1] = ((uint4*)vals)[1];
}

// --- Transpose + fp32->bf16 cast into K-CHUNKED layout: (R,Cc) -> [R/64][Cc][64] ---
__global__ __launch_bounds__(256) void transpose_cast_kernel(
    const float* __restrict__ src, __bf16* __restrict__ dst, int R, int Cc) {
  int e = blockIdx.z;
  src += (size_t)e * R * Cc;
  dst += (size_t)e * R * Cc;
  __shared__ float tile[64][65];
  int gy = blockIdx.y * 64;  // src row base (out col base)
  int gx = blockIdx.x * 64;  // src col base (out row base)
  int tid = threadIdx.x;
  int r = tid >> 4;
  int c4 = (tid & 15) * 4;
#pragma unroll
  for (int rr = 0; rr < 4; ++rr) {
    float4 v = *(const float4*)(src + (size_t)(gy + r + rr * 16) * Cc + gx + c4);
    tile[r + rr * 16][c4 + 0] = v.x;
    tile[r + rr * 16][c4 + 1] = v.y;
    tile[r + rr * 16][c4 + 2] = v.z;
    tile[r + rr * 16][c4 + 3] = v.w;
  }
  __syncthreads();
  int r2 = tid >> 2;          // out row offset (= src col) 0..63
  int cb = (tid & 3) * 16;    // out col chunk-offset within the 64-col chunk
  __bf16 o[16] __attribute__((aligned(16)));
#pragma unroll
  for (int i = 0; i < 16; ++i) o[i] = (__bf16)tile[cb + i][r2];
  uint4* dp = (uint4*)(dst + ((size_t)(gy >> 6) * Cc + gx + r2) * 64 + cb);
  dp[0] = ((uint4*)o)[0];
  dp[1] = ((uint4*)o)[1];
}

// ---- MFMA GEMM: 256x256 tile, BK=32, fine-phase schedule (T3+T4+T5), 96KB LDS ----
// Diagnosis: rounds 0-3 (all 2-barrier-per-K-tile macro schedules) pinned at
// MfmaUtil 16-18% across tile/occupancy/depth/layout changes == m233's measured
// ~25% structural ceiling. This port follows the m201/m218 fine-phase template:
// per K-tile, TWO phases, each:
//   { ds_read subtile (8 or 4 b128) ; stage ONE operand of tile t+2 (2 gld16) ;
//     s_barrier ; lgkmcnt(0) ; setprio(1) ; 16 MFMA ; setprio(0) ; s_barrier }
// Counted vmcnt ONCE per K-tile (before the tile's final barrier): vmcnt(4)
// retires exactly tile t+1's 4 loads; tile t+2's 4 stay in flight (never
// vmcnt(0) in steady state — T4). Ring: 3 bufs x 32KB.
// WAR ledger: stage(t+2) writes buf[(t+2)%3] == buf[(t-1)%3]; its reads drained
// before t-1's final barrier (lgkm waits precede MFMA uses), stage issues after
// -> no race (same proof as verified round-1 ring).
// RAW ledger: tile t's 4 loads issued during t-2's phases; retired by the
// vmcnt(4) before t-1's final barrier; barrier makes all waves' DMA visible
// before t's phase-0 ds_reads.
// LDS image/swizzle identical to verified rounds: 64B rows, 16B chunk XOR
// (chunk ^ (row>>1)&3) applied to global SOURCE (gld_lds dest linear, rule #21)
// and to fragment reads. 0 bank conflicts measured.
// K-CHUNKED operands (round 3): [e][k/64][row][64]; BK=32 reads the (kg&1) 64B
// half of each 128B chunk-row (other half read at kg+1 -> L2-resident).
template <int EPI, int KSPLIT>
__global__ __launch_bounds__(512, 2) void moe_gemm_kernel(
    const __bf16* __restrict__ A, const __bf16* __restrict__ Bt,
    const float* __restrict__ bias, __bf16* __restrict__ Hout,
    const int* __restrict__ slot_token, const float* __restrict__ slot_prob,
    float* __restrict__ out, int M, int N, int Kd) {
  // --- bijective chunked XCD swizzle (nwg % 8 == 0) ---
  const int nwg = gridDim.x * gridDim.y * gridDim.z;
  int flat = (blockIdx.z * gridDim.y + blockIdx.y) * gridDim.x + blockIdx.x;
  flat = (flat & 7) * (nwg >> 3) + (flat >> 3);
  const int bx = flat % gridDim.x;
  int tmpf = flat / gridDim.x;
  const int by = tmpf % gridDim.y;
  const int bz = tmpf / gridDim.y;

  const int e  = bz / KSPLIT;
  const int ks = bz % KSPLIT;
  const int m0 = by * 256, n0 = bx * 256;
  __shared__ __bf16 lds[3 * 16384];  // 3 ring bufs x (A 256x32 + B 256x32) = 96KB
  const int tid = threadIdx.x, wave = tid >> 6, lane = tid & 63;
  const int quad = lane >> 4, l15 = lane & 15;
  const int wm = (wave >> 2) * 128, wn = (wave & 3) * 64;
  f32x4 acc[8][4] = {};
  const int ktiles = (Kd / KSPLIT) >> 5;      // K-tiles of 32 for this split
  const size_t slabA = (size_t)M * 128;       // bytes per 64-wide A chunk-slab
  const size_t slabB = (size_t)N * 128;

  // Staging geometry: per phase each thread moves 2x16B of ONE operand (16KB).
  // LDS dest (linear): wave*2048 + rr*1024 + lane*16 -> row = wave*32+rr*16+(lane>>2),
  // chunk16 = lane&3. Source chunk pre-swizzled with (row>>1)&3 == (lane>>3)&3.
  const int lrow0 = wave * 32 + (lane >> 2);
  const int swz = ((lane & 3) ^ ((lane >> 3) & 3)) * 16;
  const char* pA0 = (const char*)A + (size_t)e * (Kd >> 6) * slabA
                    + (size_t)(m0 + lrow0) * 128 + swz;
  const char* pB0 = (const char*)Bt + (size_t)e * (Kd >> 6) * slabB
                    + (size_t)(n0 + lrow0) * 128 + swz;
  const int dlo = wave * 2048 + lane * 16;
  const int kgbase = ks * ktiles;

  auto stage_op = [&](int t, int b, int isB) {
    int kg = kgbase + t;
    char* dst = (char*)lds + b * 32768 + isB * 16384 + dlo;
    const char* s = (isB ? pB0 : pA0)
                    + (size_t)(kg >> 1) * (isB ? slabB : slabA) + (kg & 1) * 64;
    gld16(s,               dst);
    gld16(s + 16 * 128,    dst + 1024);   // +16 rows
  };

  // Fragment read offsets (bytes, tile-local; 64B rows).
  int aoff[8], boff[4];
#pragma unroll
  for (int i = 0; i < 8; ++i) aoff[i] = (wm + i * 16 + l15) * 64;
#pragma unroll
  for (int j = 0; j < 4; ++j) boff[j] = (wn + j * 16 + l15) * 64;
  const int coff = ((quad ^ ((l15 >> 1) & 3)) * 16);

  // Prologue: stage tiles 0,1; retire tile 0 (leave tile 1 in flight); sync.
  stage_op(0, 0, 0); stage_op(0, 0, 1);
  if (ktiles > 1) { stage_op(1, 1, 0); stage_op(1, 1, 1); }
  if (ktiles > 1) __builtin_amdgcn_s_waitcnt(0x0f74);  // vmcnt(4)
  else            __builtin_amdgcn_s_waitcnt(0x0f70);  // vmcnt(0)
  __builtin_amdgcn_s_barrier();

  int bcur = 0, bstage = 2;
  for (int t = 0; t < ktiles; ++t) {
    const char* La = (const char*)lds + bcur * 32768;
    const char* Lb = La + 16384;
    bf16x8 av[4], bv[4];
    // ---- phase 0: read bv + av[0..3]; stage A of t+2; MFMA upper half ----
#pragma unroll
    for (int j = 0; j < 4; ++j) bv[j] = *(const bf16x8*)(Lb + boff[j] + coff);
#pragma unroll
    for (int i = 0; i < 4; ++i) av[i] = *(const bf16x8*)(La + aoff[i] + coff);
    if (t + 2 < ktiles) stage_op(t + 2, bstage, 0);
    __builtin_amdgcn_s_barrier();
    __builtin_amdgcn_s_waitcnt(0xc07f);  // lgkmcnt(0)
    __builtin_amdgcn_s_setprio(1);
#pragma unroll
    for (int i = 0; i < 4; ++i)
#pragma unroll
      for (int j = 0; j < 4; ++j)
        acc[i][j] = __builtin_amdgcn_mfma_f32_16x16x32_bf16(av[i], bv[j], acc[i][j], 0, 0, 0);
    __builtin_amdgcn_s_setprio(0);
    __builtin_amdgcn_s_barrier();
    // ---- phase 1: read av[4..7]; stage B of t+2; MFMA lower half ----
#pragma unroll
    for (int i = 0; i < 4; ++i) av[i] = *(const bf16x8*)(La + aoff[4 + i] + coff);
    if (t + 2 < ktiles) stage_op(t + 2, bstage, 1);
    __builtin_amdgcn_s_barrier();
    __builtin_amdgcn_s_waitcnt(0xc07f);  // lgkmcnt(0)
    __builtin_amdgcn_s_setprio(1);
#pragma unroll
    for (int i = 0; i < 4; ++i)
#pragma unroll
      for (int j = 0; j < 4; ++j)
        acc[4 + i][j] = __builtin_amdgcn_mfma_f32_16x16x32_bf16(av[i], bv[j], acc[4 + i][j], 0, 0, 0);
    __builtin_amdgcn_s_setprio(0);
    // Retire tile t+1 (next tile's data) before its reads; t+2's 4 stay in flight.
    if (t + 1 < ktiles) {
      if (t + 2 < ktiles) __builtin_amdgcn_s_waitcnt(0x0f74);  // vmcnt(4)
      else                __builtin_amdgcn_s_waitcnt(0x0f70);  // vmcnt(0)
    }
    __builtin_amdgcn_s_barrier();
    bcur = (bcur == 2) ? 0 : bcur + 1;
    bstage = (bstage == 2) ? 0 : bstage + 1;
  }

  // Epilogue. C/D layout: col = lane&15, row = quad*4 + reg  [verified m89/m91]
  if (EPI == 1) {
    // Write Hout K-CHUNKED: [e][N/64][M][64]. Chunk = (n0+wn)>>6 (wave-uniform).
    __bf16* He = Hout + (size_t)e * M * N;
    const size_t kfbase = (size_t)((n0 + wn) >> 6) * M;
    float bj[4];
#pragma unroll
    for (int j = 0; j < 4; ++j) bj[j] = bias[(size_t)e * N + n0 + wn + j * 16 + l15];
#pragma unroll
    for (int i = 0; i < 8; ++i) {
#pragma unroll
      for (int r = 0; r < 4; ++r) {
        int m = m0 + wm + i * 16 + quad * 4 + r;
#pragma unroll
        for (int j = 0; j < 4; ++j) {
          float v = acc[i][j][r] + bj[j];
          // tanh-approx GELU (JAX default approximate=True)
          float u = 0.7978845608028654f * (v + 0.044715f * v * v * v);
          float ex = __expf(-2.f * fabsf(u));
          float th = (1.f - ex) / (1.f + ex);
          th = copysignf(th, u);
          He[(kfbase + m) * 64 + j * 16 + l15] = (__bf16)(0.5f * v * (1.f + th));
        }
      }
    }
  } else {
    const int* st = slot_token + e * CAP;
    const float* sp = slot_prob + e * CAP;
    float bj[4];
#pragma unroll
    for (int j = 0; j < 4; ++j)
      bj[j] = (ks == 0) ? bias[(size_t)e * N + n0 + wn + j * 16 + l15] : 0.f;
#pragma unroll
    for (int i = 0; i < 8; ++i) {
#pragma unroll
      for (int r = 0; r < 4; ++r) {
        int m = m0 + wm + i * 16 + quad * 4 + r;
        int tok = st[m];
        if (tok >= 0) {
          float p = sp[m];
#pragma unroll
          for (int j = 0; j < 4; ++j) {
            int n = n0 + wn + j * 16 + l15;
            float v = acc[i][j][r] + bj[j];
            atomicAdd(out + (size_t)tok * HDIM + n, p * v);
          }
        }
      }
    }
  }
}

extern "C" void kernel_launch(void* const* d_in, const int* in_sizes, int n_in,
                              void* d_out, int out_size, void* d_ws, size_t ws_size,
                              hipStream_t stream) {
  const float* x  = (const float*)d_in[0];
  const float* wr = (const float*)d_in[1];
  const float* w1 = (const float*)d_in[2];
  const float* b1 = (const float*)d_in[3];
  const float* w2 = (const float*)d_in[4];
  const float* b2 = (const float*)d_in[5];
  float* out = (float*)d_out;

  // Workspace layout (bytes). All GEMM operands K-CHUNKED: [e][k/64][row][64] bf16.
  char* ws = (char*)d_ws;
  size_t off = 0;
  __bf16* w1t = (__bf16*)(ws + off); off += (size_t)NEXP * FDIM * HDIM * 2;   // 64MB [e][H/64][F][64]
  __bf16* w2t = (__bf16*)(ws + off); off += (size_t)NEXP * HDIM * FDIM * 2;   // 64MB [e][F/64][H][64]
  __bf16* disp = (__bf16*)(ws + off); off += (size_t)NEXP * CAP * HDIM * 2;   // 40MB [e][H/64][C][64]
  __bf16* hbuf = (__bf16*)(ws + off); off += (size_t)NEXP * CAP * FDIM * 2;   // 80MB [e][F/64][C][64]
  int*   slot_token = (int*)(ws + off);  off += (size_t)NEXP * CAP * 4;
  float* slot_prob  = (float*)(ws + off); off += (size_t)NEXP * CAP * 4;
  int*   eidx  = (int*)(ws + off);  off += (size_t)T_TOK * 2 * 4;
  float* eprob = (float*)(ws + off); off += (size_t)T_TOK * 2 * 4;
  if (ws_size < off) return;  // insufficient scratch

  // Init: empty slots = -1, output accumulates via atomics
  hipMemsetAsync(slot_token, 0xFF, (size_t)NEXP * CAP * 4, stream);
  hipMemsetAsync(d_out, 0, (size_t)T_TOK * HDIM * 4, stream);

  // Weight transpose+cast into chunked layouts:
  // w1 (E,H,F) -> w1t [e][H/64][F][64]; w2 (E,F,H) -> w2t [e][F/64][H][64]
  transpose_cast_kernel<<<dim3(FDIM / 64, HDIM / 64, NEXP), 256, 0, stream>>>(w1, w1t, HDIM, FDIM);
  transpose_cast_kernel<<<dim3(HDIM / 64, FDIM / 64, NEXP), 256, 0, stream>>>(w2, w2t, FDIM, HDIM);

  // Routing
  router_kernel<<<T_TOK / 4, 256, 0, stream>>>(x, wr, eidx, eprob);
  pos_kernel<<<1, 256, 0, stream>>>(eidx, eprob, slot_token, slot_prob);
  scatter_kernel<<<NEXP * CAP / 4, 256, 0, stream>>>(x, slot_token, disp);

  // Expert FFN: 256x256 tiles, BK=32 fine-phase schedule, chunked operands.
  // GEMM1 grid 8x5x16=640 (%8==0 for XCD swizzle). GEMM2 split-K=2: 4x5x32=640.
  moe_gemm_kernel<1, 1><<<dim3(FDIM / 256, CAP / 256, NEXP), 512, 0, stream>>>(
      disp, w1t, b1, hbuf, nullptr, nullptr, nullptr, CAP, FDIM, HDIM);
  moe_gemm_kernel<2, 2><<<dim3(HDIM / 256, CAP / 256, NEXP * 2), 512, 0, stream>>>(
      hbuf, w2t, b2, nullptr, slot_token, slot_prob, out, CAP, HDIM, FDIM);
}